// Round 2
// baseline (2993.572 us; speedup 1.0000x reference)
//
#include <hip/hip_runtime.h>
#include <hip/hip_bf16.h>

#define N_NODES 100000
#define N_EDGES 800000
#define K_DIM 256
#define N_DIM 256

// ---------------------------------------------------------------------------
// Kernel 1: out[n][c] = bias[c]
// ---------------------------------------------------------------------------
__global__ __launch_bounds__(256) void init_out_kernel(float* __restrict__ out,
                                                       const float* __restrict__ bias,
                                                       int total) {
    int i = blockIdx.x * 256 + threadIdx.x;
    if (i < total) out[i] = bias[i & (N_DIM - 1)];
}

// ---------------------------------------------------------------------------
// Kernel 2: S = X @ W   (M x 256) = (M x 256)(256 x 256), fp32 VALU GEMM
// 64x64 tile per block, BK=16, 256 threads, 4x4 register blocking.
// ---------------------------------------------------------------------------
#define BM 64
#define BN 64
#define BK 16

__global__ __launch_bounds__(256) void gemm_kernel(const float* __restrict__ X,
                                                   const float* __restrict__ W,
                                                   float* __restrict__ S,
                                                   int M) {
    __shared__ float As[BK][BM + 4];
    __shared__ float Bs[BK][BN + 4];

    const int row0 = blockIdx.x * BM;
    const int col0 = blockIdx.y * BN;
    const int tid  = threadIdx.x;
    const int tx   = tid & 15;   // 0..15  -> col group
    const int ty   = tid >> 4;   // 0..15  -> row group

    float acc[4][4] = {};

    for (int k0 = 0; k0 < K_DIM; k0 += BK) {
        // Load A tile: 64 rows x 16 k. thread (ty,tx): m = ty + i*16, k = tx
        #pragma unroll
        for (int i = 0; i < 4; ++i) {
            int m  = ty + i * 16;
            int gr = row0 + m;
            As[tx][m] = (gr < M) ? X[(size_t)gr * K_DIM + k0 + tx] : 0.f;
        }
        // Load B tile: 16 k x 64 n. thread: k = tid/64 + i*4, n = tid%64
        #pragma unroll
        for (int i = 0; i < 4; ++i) {
            int k = (tid >> 6) + i * 4;
            int n = tid & 63;
            Bs[k][n] = W[(size_t)(k0 + k) * N_DIM + col0 + n];
        }
        __syncthreads();

        #pragma unroll
        for (int k = 0; k < BK; ++k) {
            float a[4], b[4];
            #pragma unroll
            for (int i = 0; i < 4; ++i) a[i] = As[k][ty * 4 + i];
            #pragma unroll
            for (int j = 0; j < 4; ++j) b[j] = Bs[k][tx * 4 + j];
            #pragma unroll
            for (int i = 0; i < 4; ++i)
                #pragma unroll
                for (int j = 0; j < 4; ++j)
                    acc[i][j] += a[i] * b[j];
        }
        __syncthreads();
    }

    #pragma unroll
    for (int i = 0; i < 4; ++i) {
        int gr = row0 + ty * 4 + i;
        if (gr < M) {
            #pragma unroll
            for (int j = 0; j < 4; ++j)
                S[(size_t)gr * N_DIM + col0 + tx * 4 + j] = acc[i][j];
        }
    }
}

// ---------------------------------------------------------------------------
// Kernel 3: for each edge e: out[dst[e]][:] += S[src[e]][:] * w[e]
// 64 lanes per edge (float4 per lane), 4 edges per 256-thread block.
// ---------------------------------------------------------------------------
__global__ __launch_bounds__(256) void scatter_kernel(const float* __restrict__ S,
                                                      const float* __restrict__ ew,
                                                      const int* __restrict__ esrc,
                                                      const int* __restrict__ edst,
                                                      float* __restrict__ out,
                                                      int E) {
    const int tid  = threadIdx.x;
    const int e    = blockIdx.x * 4 + (tid >> 6);
    if (e >= E) return;
    const int lane = tid & 63;

    const int   s = esrc[e];
    const int   d = edst[e];
    const float w = ew[e];

    const float4 v = *reinterpret_cast<const float4*>(S + (size_t)s * N_DIM + lane * 4);
    float* o = out + (size_t)d * N_DIM + lane * 4;

    unsafeAtomicAdd(o + 0, v.x * w);
    unsafeAtomicAdd(o + 1, v.y * w);
    unsafeAtomicAdd(o + 2, v.z * w);
    unsafeAtomicAdd(o + 3, v.w * w);
}

// ---------------------------------------------------------------------------
extern "C" void kernel_launch(void* const* d_in, const int* in_sizes, int n_in,
                              void* d_out, int out_size, void* d_ws, size_t ws_size,
                              hipStream_t stream) {
    const float* x      = (const float*)d_in[0];   // [100000, 256]
    const float* weight = (const float*)d_in[1];   // [256, 256]
    const float* bias   = (const float*)d_in[2];   // [1, 256]
    const float* ew     = (const float*)d_in[3];   // [800000]
    const int*   esrc   = (const int*)d_in[4];     // [800000]
    const int*   edst   = (const int*)d_in[5];     // [800000]
    float*       out    = (float*)d_out;           // [100000, 256]
    float*       supp   = (float*)d_ws;            // [100000, 256] scratch

    // 1) out = bias (broadcast)
    {
        int total  = N_NODES * N_DIM;
        int blocks = (total + 255) / 256;
        init_out_kernel<<<blocks, 256, 0, stream>>>(out, bias, total);
    }

    // 2) supp = x @ weight
    {
        dim3 grid((N_NODES + BM - 1) / BM, N_DIM / BN);
        gemm_kernel<<<grid, 256, 0, stream>>>(x, weight, supp, N_NODES);
    }

    // 3) scatter-add over edges
    {
        int blocks = (N_EDGES + 3) / 4;
        scatter_kernel<<<blocks, 256, 0, stream>>>(supp, ew, esrc, edst, out, N_EDGES);
    }
}

// Round 3
// 688.008 us; speedup vs baseline: 4.3511x; 4.3511x over previous
//
#include <hip/hip_runtime.h>
#include <hip/hip_bf16.h>

#define N_NODES 100000
#define N_EDGES 800000
#define K_DIM 256
#define N_DIM 256

// ---------------------------------------------------------------------------
// GEMM: S = X @ W   (M x 256) = (M x 256)(256 x 256), fp32 VALU GEMM
// 64x64 tile per block, BK=16, 256 threads, 4x4 register blocking.
// ---------------------------------------------------------------------------
#define BM 64
#define BN 64
#define BK 16

__global__ __launch_bounds__(256) void gemm_kernel(const float* __restrict__ X,
                                                   const float* __restrict__ W,
                                                   float* __restrict__ S,
                                                   int M) {
    __shared__ float As[BK][BM + 4];
    __shared__ float Bs[BK][BN + 4];

    const int row0 = blockIdx.x * BM;
    const int col0 = blockIdx.y * BN;
    const int tid  = threadIdx.x;
    const int tx   = tid & 15;
    const int ty   = tid >> 4;

    float acc[4][4] = {};

    for (int k0 = 0; k0 < K_DIM; k0 += BK) {
        #pragma unroll
        for (int i = 0; i < 4; ++i) {
            int m  = ty + i * 16;
            int gr = row0 + m;
            As[tx][m] = (gr < M) ? X[(size_t)gr * K_DIM + k0 + tx] : 0.f;
        }
        #pragma unroll
        for (int i = 0; i < 4; ++i) {
            int k = (tid >> 6) + i * 4;
            int n = tid & 63;
            Bs[k][n] = W[(size_t)(k0 + k) * N_DIM + col0 + n];
        }
        __syncthreads();

        #pragma unroll
        for (int k = 0; k < BK; ++k) {
            float a[4], b[4];
            #pragma unroll
            for (int i = 0; i < 4; ++i) a[i] = As[k][ty * 4 + i];
            #pragma unroll
            for (int j = 0; j < 4; ++j) b[j] = Bs[k][tx * 4 + j];
            #pragma unroll
            for (int i = 0; i < 4; ++i)
                #pragma unroll
                for (int j = 0; j < 4; ++j)
                    acc[i][j] += a[i] * b[j];
        }
        __syncthreads();
    }

    #pragma unroll
    for (int i = 0; i < 4; ++i) {
        int gr = row0 + ty * 4 + i;
        if (gr < M) {
            #pragma unroll
            for (int j = 0; j < 4; ++j)
                S[(size_t)gr * N_DIM + col0 + tx * 4 + j] = acc[i][j];
        }
    }
}

// ---------------------------------------------------------------------------
// CSR build kernels (by dst)
// ---------------------------------------------------------------------------
__global__ __launch_bounds__(256) void count_kernel(const int* __restrict__ edst,
                                                    int* __restrict__ counts, int E) {
    int e = blockIdx.x * 256 + threadIdx.x;
    if (e < E) atomicAdd(&counts[edst[e]], 1);
}

// Single-block exclusive scan: offsets[0]=0, offsets[i+1]=sum(counts[0..i]).
#define SCAN_T 1024
#define CHUNK ((N_NODES + SCAN_T - 1) / SCAN_T)   // 98

__global__ __launch_bounds__(SCAN_T) void scan_kernel(const int* __restrict__ counts,
                                                      int* __restrict__ offsets) {
    __shared__ int sums[SCAN_T];
    const int t     = threadIdx.x;
    const int begin = t * CHUNK;
    const int end   = min(begin + CHUNK, N_NODES);

    int s = 0;
    for (int i = begin; i < end; ++i) s += counts[i];
    sums[t] = s;
    __syncthreads();

    // Hillis-Steele inclusive scan over thread sums
    for (int st = 1; st < SCAN_T; st <<= 1) {
        int v = (t >= st) ? sums[t - st] : 0;
        __syncthreads();
        sums[t] += v;
        __syncthreads();
    }

    int run = (t == 0) ? 0 : sums[t - 1];   // exclusive prefix of this chunk
    if (t == 0) offsets[0] = 0;
    for (int i = begin; i < end; ++i) {
        run += counts[i];
        offsets[i + 1] = run;
    }
}

// Fill CSR with (src, weight) pairs.
__global__ __launch_bounds__(256) void fill_kernel(const int* __restrict__ esrc,
                                                   const int* __restrict__ edst,
                                                   const float* __restrict__ ew,
                                                   const int* __restrict__ offsets,
                                                   int* __restrict__ cursor,
                                                   int2* __restrict__ csr, int E) {
    int e = blockIdx.x * 256 + threadIdx.x;
    if (e >= E) return;
    int d   = edst[e];
    int pos = offsets[d] + atomicAdd(&cursor[d], 1);
    csr[pos] = make_int2(esrc[e], __float_as_int(ew[e]));
}

// ---------------------------------------------------------------------------
// Gather: one 64-lane wave per dst node. acc = bias + sum_j w_j * supp[src_j].
// Each lane owns a float4 column slice (lane*4 .. lane*4+3). Single write.
// ---------------------------------------------------------------------------
__global__ __launch_bounds__(256) void gather_kernel(const float* __restrict__ S,
                                                     const float* __restrict__ bias,
                                                     const int* __restrict__ offsets,
                                                     const int2* __restrict__ csr,
                                                     float* __restrict__ out) {
    const int tid  = threadIdx.x;
    const int node = blockIdx.x * 4 + (tid >> 6);
    if (node >= N_NODES) return;
    const int lane = tid & 63;

    const int row = offsets[node];
    const int end = offsets[node + 1];

    float4 acc = *reinterpret_cast<const float4*>(bias + lane * 4);

    for (int j = row; j < end; ++j) {
        const int2  p = csr[j];              // wave-uniform -> L1 broadcast
        const float w = __int_as_float(p.y);
        const float4 v = *reinterpret_cast<const float4*>(S + (size_t)p.x * N_DIM + lane * 4);
        acc.x += v.x * w;
        acc.y += v.y * w;
        acc.z += v.z * w;
        acc.w += v.w * w;
    }

    *reinterpret_cast<float4*>(out + (size_t)node * N_DIM + lane * 4) = acc;
}

// ---------------------------------------------------------------------------
// Fallback path kernels (only if ws_size too small for CSR — old atomic route)
// ---------------------------------------------------------------------------
__global__ __launch_bounds__(256) void init_out_kernel(float* __restrict__ out,
                                                       const float* __restrict__ bias,
                                                       int total) {
    int i = blockIdx.x * 256 + threadIdx.x;
    if (i < total) out[i] = bias[i & (N_DIM - 1)];
}

__global__ __launch_bounds__(256) void scatter_kernel(const float* __restrict__ S,
                                                      const float* __restrict__ ew,
                                                      const int* __restrict__ esrc,
                                                      const int* __restrict__ edst,
                                                      float* __restrict__ out, int E) {
    const int tid  = threadIdx.x;
    const int e    = blockIdx.x * 4 + (tid >> 6);
    if (e >= E) return;
    const int lane = tid & 63;
    const int   s = esrc[e];
    const int   d = edst[e];
    const float w = ew[e];
    const float4 v = *reinterpret_cast<const float4*>(S + (size_t)s * N_DIM + lane * 4);
    float* o = out + (size_t)d * N_DIM + lane * 4;
    unsafeAtomicAdd(o + 0, v.x * w);
    unsafeAtomicAdd(o + 1, v.y * w);
    unsafeAtomicAdd(o + 2, v.z * w);
    unsafeAtomicAdd(o + 3, v.w * w);
}

// ---------------------------------------------------------------------------
extern "C" void kernel_launch(void* const* d_in, const int* in_sizes, int n_in,
                              void* d_out, int out_size, void* d_ws, size_t ws_size,
                              hipStream_t stream) {
    const float* x      = (const float*)d_in[0];
    const float* weight = (const float*)d_in[1];
    const float* bias   = (const float*)d_in[2];
    const float* ew     = (const float*)d_in[3];
    const int*   esrc   = (const int*)d_in[4];
    const int*   edst   = (const int*)d_in[5];
    float*       out    = (float*)d_out;

    // Workspace layout
    char*  ws      = (char*)d_ws;
    const size_t SUPP_B   = (size_t)N_NODES * N_DIM * 4;       // 102,400,000
    const size_t CNT_B    = (size_t)N_NODES * 4;               //     400,000
    const size_t OFF_B    = ((size_t)(N_NODES + 1) * 4 + 15) & ~(size_t)15;
    const size_t CSR_B    = (size_t)N_EDGES * 8;               //   6,400,000

    float* supp    = (float*)(ws);
    int*   counts  = (int*)  (ws + SUPP_B);
    int*   cursor  = (int*)  (ws + SUPP_B + CNT_B);
    int*   offsets = (int*)  (ws + SUPP_B + 2 * CNT_B);
    int2*  csr     = (int2*) (ws + SUPP_B + 2 * CNT_B + OFF_B);
    const size_t NEEDED = SUPP_B + 2 * CNT_B + OFF_B + CSR_B;

    // 1) supp = x @ weight (fp32 VALU GEMM)
    {
        dim3 grid((N_NODES + BM - 1) / BM, N_DIM / BN);
        gemm_kernel<<<grid, 256, 0, stream>>>(x, weight, supp, N_NODES);
    }

    if (ws_size >= NEEDED) {
        // 2) zero counters (ws is poisoned each call)
        hipMemsetAsync(counts, 0, 2 * CNT_B, stream);
        // 3) CSR by dst
        count_kernel<<<(N_EDGES + 255) / 256, 256, 0, stream>>>(edst, counts, N_EDGES);
        scan_kernel<<<1, SCAN_T, 0, stream>>>(counts, offsets);
        fill_kernel<<<(N_EDGES + 255) / 256, 256, 0, stream>>>(esrc, edst, ew, offsets,
                                                               cursor, csr, N_EDGES);
        // 4) gather + bias, one wave per node
        gather_kernel<<<(N_NODES + 3) / 4, 256, 0, stream>>>(supp, bias, offsets, csr, out);
    } else {
        // Fallback: atomic scatter path
        int total  = N_NODES * N_DIM;
        init_out_kernel<<<(total + 255) / 256, 256, 0, stream>>>(out, bias, total);
        scatter_kernel<<<(N_EDGES + 3) / 4, 256, 0, stream>>>(supp, ew, esrc, edst, out, N_EDGES);
    }
}

// Round 4
// 467.336 us; speedup vs baseline: 6.4056x; 1.4722x over previous
//
#include <hip/hip_runtime.h>
#include <hip/hip_bf16.h>

#define N_NODES 100000
#define N_EDGES 800000
#define K_DIM 256
#define N_DIM 256

typedef __attribute__((ext_vector_type(8)))  short  short8;   // 8 bf16 (4 VGPR)
typedef __attribute__((ext_vector_type(4)))  float  f32x4;    // MFMA C/D frag
typedef __attribute__((ext_vector_type(4)))  float  float4v;

__device__ short g_Wt[K_DIM * N_DIM];   // Wt[n][k] = bf16(W[k][n]), 128 KiB
__device__ int   g_bsums[512];
__device__ int   g_boff[512];

static __device__ inline short f32_to_bf16s(float f) {
    __bf16 h = (__bf16)f;                       // RNE convert (v_cvt)
    return __builtin_bit_cast(short, h);
}

// ---------------------------------------------------------------------------
// W transpose+convert: Wt[n][k] = bf16(W[k][n]). 256 blocks x 256 threads.
// ---------------------------------------------------------------------------
__global__ __launch_bounds__(256) void convert_w_kernel(const float* __restrict__ W) {
    const int n = blockIdx.x;
    const int k = threadIdx.x;
    g_Wt[n * K_DIM + k] = f32_to_bf16s(W[(size_t)k * N_DIM + n]);
}

// ---------------------------------------------------------------------------
// MFMA GEMM: S = X @ W  via bf16 16x16x32, fp32 accum. No LDS.
// Block: 256 thr = 4 waves. BM=64 rows, full N=256 (wave w -> cols w*64..+63).
// A frag: row = m0+mi*16+(lane&15), k = k0+(lane>>4)*8+j  (fp32 load + cvt)
// B frag: col = wc+ni*16+(lane&15), same k  (short8 from g_Wt, 16B load)
// C/D   : col = lane&15, row = (lane>>4)*4 + reg          [m89-verified]
// ---------------------------------------------------------------------------
__global__ __launch_bounds__(256) void mfma_gemm_kernel(const float* __restrict__ X,
                                                        float* __restrict__ S,
                                                        int M) {
    const int wave = threadIdx.x >> 6;
    const int lane = threadIdx.x & 63;
    const int r    = lane & 15;
    const int kg   = lane >> 4;
    const int m0   = blockIdx.x * 64;
    const int wc   = wave * 64;

    f32x4 acc[4][4];
    #pragma unroll
    for (int i = 0; i < 4; ++i)
        #pragma unroll
        for (int j = 0; j < 4; ++j)
            acc[i][j] = (f32x4)0.f;

    #pragma unroll
    for (int k0 = 0; k0 < K_DIM; k0 += 32) {
        short8 a[4], b[4];
        #pragma unroll
        for (int mi = 0; mi < 4; ++mi) {
            int row = m0 + mi * 16 + r;
            row = row < M ? row : (M - 1);
            const float* p = X + (size_t)row * K_DIM + k0 + kg * 8;
            float4v lo = *reinterpret_cast<const float4v*>(p);
            float4v hi = *reinterpret_cast<const float4v*>(p + 4);
            short8 v;
            v[0] = f32_to_bf16s(lo[0]); v[1] = f32_to_bf16s(lo[1]);
            v[2] = f32_to_bf16s(lo[2]); v[3] = f32_to_bf16s(lo[3]);
            v[4] = f32_to_bf16s(hi[0]); v[5] = f32_to_bf16s(hi[1]);
            v[6] = f32_to_bf16s(hi[2]); v[7] = f32_to_bf16s(hi[3]);
            a[mi] = v;
        }
        #pragma unroll
        for (int ni = 0; ni < 4; ++ni) {
            const short* q = g_Wt + (size_t)(wc + ni * 16 + r) * K_DIM + k0 + kg * 8;
            b[ni] = *reinterpret_cast<const short8*>(q);
        }
        #pragma unroll
        for (int mi = 0; mi < 4; ++mi)
            #pragma unroll
            for (int ni = 0; ni < 4; ++ni)
                acc[mi][ni] = __builtin_amdgcn_mfma_f32_16x16x32_bf16(a[mi], b[ni], acc[mi][ni], 0, 0, 0);
    }

    #pragma unroll
    for (int mi = 0; mi < 4; ++mi) {
        #pragma unroll
        for (int reg = 0; reg < 4; ++reg) {
            const int row = m0 + mi * 16 + kg * 4 + reg;
            if (row < M) {
                #pragma unroll
                for (int ni = 0; ni < 4; ++ni)
                    S[(size_t)row * N_DIM + wc + ni * 16 + r] = acc[mi][ni][reg];
            }
        }
    }
}

// ---------------------------------------------------------------------------
// CSR build (by dst): count -> 3-stage scan -> fill
// ---------------------------------------------------------------------------
__global__ __launch_bounds__(256) void count_kernel(const int* __restrict__ edst,
                                                    int* __restrict__ counts, int E) {
    int e = blockIdx.x * 256 + threadIdx.x;
    if (e < E) atomicAdd(&counts[edst[e]], 1);
}

#define SCAN_NB ((N_NODES + 255) / 256)   // 391

__global__ __launch_bounds__(256) void scan1_kernel(const int* __restrict__ counts) {
    __shared__ int ws[4];
    const int i = blockIdx.x * 256 + threadIdx.x;
    int v = (i < N_NODES) ? counts[i] : 0;
    #pragma unroll
    for (int st = 32; st > 0; st >>= 1) v += __shfl_down(v, st, 64);
    if ((threadIdx.x & 63) == 0) ws[threadIdx.x >> 6] = v;
    __syncthreads();
    if (threadIdx.x == 0) g_bsums[blockIdx.x] = ws[0] + ws[1] + ws[2] + ws[3];
}

__global__ __launch_bounds__(512) void scan2_kernel() {
    __shared__ int s[512];
    const int t = threadIdx.x;
    int v = (t < SCAN_NB) ? g_bsums[t] : 0;
    s[t] = v;
    __syncthreads();
    for (int st = 1; st < 512; st <<= 1) {
        int u = (t >= st) ? s[t - st] : 0;
        __syncthreads();
        s[t] += u;
        __syncthreads();
    }
    g_boff[t] = s[t] - v;   // exclusive prefix
}

__global__ __launch_bounds__(256) void scan3_kernel(const int* __restrict__ counts,
                                                    int* __restrict__ offsets) {
    __shared__ int s[256];
    const int t = threadIdx.x;
    const int i = blockIdx.x * 256 + t;
    int v = (i < N_NODES) ? counts[i] : 0;
    s[t] = v;
    __syncthreads();
    for (int st = 1; st < 256; st <<= 1) {
        int u = (t >= st) ? s[t - st] : 0;
        __syncthreads();
        s[t] += u;
        __syncthreads();
    }
    if (i < N_NODES) offsets[i + 1] = g_boff[blockIdx.x] + s[t];
    if (i == 0) offsets[0] = 0;
}

__global__ __launch_bounds__(256) void fill_kernel(const int* __restrict__ esrc,
                                                   const int* __restrict__ edst,
                                                   const float* __restrict__ ew,
                                                   const int* __restrict__ offsets,
                                                   int* __restrict__ cursor,
                                                   int2* __restrict__ csr, int E) {
    int e = blockIdx.x * 256 + threadIdx.x;
    if (e >= E) return;
    int d   = edst[e];
    int pos = offsets[d] + atomicAdd(&cursor[d], 1);
    csr[pos] = make_int2(esrc[e], __float_as_int(ew[e]));
}

// ---------------------------------------------------------------------------
// Gather: one wave per dst node, float4/lane, 1-deep CSR prefetch.
// ---------------------------------------------------------------------------
__global__ __launch_bounds__(256) void gather_kernel(const float* __restrict__ S,
                                                     const float* __restrict__ bias,
                                                     const int* __restrict__ offsets,
                                                     const int2* __restrict__ csr,
                                                     float* __restrict__ out) {
    const int tid  = threadIdx.x;
    const int node = blockIdx.x * 4 + (tid >> 6);
    if (node >= N_NODES) return;
    const int lane = tid & 63;

    const int row = offsets[node];
    const int end = offsets[node + 1];

    float4v acc = *reinterpret_cast<const float4v*>(bias + lane * 4);

    int2 p = (row < end) ? csr[row] : make_int2(0, 0);
    for (int j = row; j < end; ++j) {
        const int2 pn = (j + 1 < end) ? csr[j + 1] : p;
        const float w = __int_as_float(p.y);
        const float4v v = *reinterpret_cast<const float4v*>(S + (size_t)p.x * N_DIM + lane * 4);
        acc += v * w;
        p = pn;
    }

    *reinterpret_cast<float4v*>(out + (size_t)node * N_DIM + lane * 4) = acc;
}

// ---------------------------------------------------------------------------
// Fallback (ws too small): atomic scatter path
// ---------------------------------------------------------------------------
__global__ __launch_bounds__(256) void init_out_kernel(float* __restrict__ out,
                                                       const float* __restrict__ bias,
                                                       int total) {
    int i = blockIdx.x * 256 + threadIdx.x;
    if (i < total) out[i] = bias[i & (N_DIM - 1)];
}

__global__ __launch_bounds__(256) void scatter_kernel(const float* __restrict__ S,
                                                      const float* __restrict__ ew,
                                                      const int* __restrict__ esrc,
                                                      const int* __restrict__ edst,
                                                      float* __restrict__ out, int E) {
    const int tid  = threadIdx.x;
    const int e    = blockIdx.x * 4 + (tid >> 6);
    if (e >= E) return;
    const int lane = tid & 63;
    const int   s = esrc[e];
    const int   d = edst[e];
    const float w = ew[e];
    const float4v v = *reinterpret_cast<const float4v*>(S + (size_t)s * N_DIM + lane * 4);
    float* o = out + (size_t)d * N_DIM + lane * 4;
    unsafeAtomicAdd(o + 0, v[0] * w);
    unsafeAtomicAdd(o + 1, v[1] * w);
    unsafeAtomicAdd(o + 2, v[2] * w);
    unsafeAtomicAdd(o + 3, v[3] * w);
}

// ---------------------------------------------------------------------------
extern "C" void kernel_launch(void* const* d_in, const int* in_sizes, int n_in,
                              void* d_out, int out_size, void* d_ws, size_t ws_size,
                              hipStream_t stream) {
    const float* x      = (const float*)d_in[0];
    const float* weight = (const float*)d_in[1];
    const float* bias   = (const float*)d_in[2];
    const float* ew     = (const float*)d_in[3];
    const int*   esrc   = (const int*)d_in[4];
    const int*   edst   = (const int*)d_in[5];
    float*       out    = (float*)d_out;

    // Workspace layout (identical footprint to the round-3 pass)
    char*  ws     = (char*)d_ws;
    const size_t SUPP_B = (size_t)N_NODES * N_DIM * 4;
    const size_t CNT_B  = (size_t)N_NODES * 4;
    const size_t OFF_B  = ((size_t)(N_NODES + 1) * 4 + 15) & ~(size_t)15;
    const size_t CSR_B  = (size_t)N_EDGES * 8;

    float* supp    = (float*)(ws);
    int*   counts  = (int*)  (ws + SUPP_B);
    int*   cursor  = (int*)  (ws + SUPP_B + CNT_B);
    int*   offsets = (int*)  (ws + SUPP_B + 2 * CNT_B);
    int2*  csr     = (int2*) (ws + SUPP_B + 2 * CNT_B + OFF_B);
    const size_t NEEDED = SUPP_B + 2 * CNT_B + OFF_B + CSR_B;

    // 1) Wt = bf16(W^T); supp = x @ W via MFMA
    convert_w_kernel<<<N_DIM, 256, 0, stream>>>(weight);
    mfma_gemm_kernel<<<(N_NODES + 63) / 64, 256, 0, stream>>>(x, supp, N_NODES);

    if (ws_size >= NEEDED) {
        hipMemsetAsync(counts, 0, 2 * CNT_B, stream);   // counts + cursor
        count_kernel<<<(N_EDGES + 255) / 256, 256, 0, stream>>>(edst, counts, N_EDGES);
        scan1_kernel<<<SCAN_NB, 256, 0, stream>>>(counts);
        scan2_kernel<<<1, 512, 0, stream>>>();
        scan3_kernel<<<SCAN_NB, 256, 0, stream>>>(counts, offsets);
        fill_kernel<<<(N_EDGES + 255) / 256, 256, 0, stream>>>(esrc, edst, ew, offsets,
                                                               cursor, csr, N_EDGES);
        gather_kernel<<<(N_NODES + 3) / 4, 256, 0, stream>>>(supp, bias, offsets, csr, out);
    } else {
        int total = N_NODES * N_DIM;
        init_out_kernel<<<(total + 255) / 256, 256, 0, stream>>>(out, bias, total);
        scatter_kernel<<<(N_EDGES + 3) / 4, 256, 0, stream>>>(supp, ew, esrc, edst, out, N_EDGES);
    }
}

// Round 7
// 414.092 us; speedup vs baseline: 7.2292x; 1.1286x over previous
//
#include <hip/hip_runtime.h>
#include <hip/hip_bf16.h>

#define N_NODES 100000
#define N_EDGES 800000
#define K_DIM 256
#define N_DIM 256

typedef __attribute__((ext_vector_type(8)))  short  bf16x8;   // 8 bf16 (4 VGPR)
typedef __attribute__((ext_vector_type(4)))  short  bf16x4;   // 4 bf16 (2 VGPR)
typedef __attribute__((ext_vector_type(4)))  float  f32x4;

__device__ short g_Wt[K_DIM * N_DIM];   // Wt[n][k] = bf16(W[k][n]), 128 KiB
__device__ int   g_bsums[512];
__device__ int   g_boff[512];

static __device__ inline short f32_to_bf16s(float f) {
    __bf16 h = (__bf16)f;                       // RNE convert
    return __builtin_bit_cast(short, h);
}
static __device__ inline float bf16s_to_f32(short s) {
    unsigned int u = ((unsigned int)(unsigned short)s) << 16;
    return __uint_as_float(u);
}

// ---------------------------------------------------------------------------
// W transpose+convert: Wt[n][k] = bf16(W[k][n]).
// ---------------------------------------------------------------------------
__global__ __launch_bounds__(256) void convert_w_kernel(const float* __restrict__ W) {
    const int n = blockIdx.x;
    const int k = threadIdx.x;
    g_Wt[n * K_DIM + k] = f32_to_bf16s(W[(size_t)k * N_DIM + n]);
}

// ---------------------------------------------------------------------------
// MFMA GEMM: S(bf16) = X @ W via bf16 16x16x32, fp32 accum. No LDS.
// Block: 4 waves. BM=64 rows, full N=256 (wave w -> cols w*64..+63).
// A frag: row = m0+mi*16+(lane&15), k = k0+(lane>>4)*8+j  (fp32 load + cvt)
// B frag: col = wc+ni*16+(lane&15), same k  (bf16x8 from g_Wt)
// C/D   : col = lane&15, row = (lane>>4)*4 + reg          [m89-verified]
// ---------------------------------------------------------------------------
__global__ __launch_bounds__(256) void mfma_gemm_kernel(const float* __restrict__ X,
                                                        short* __restrict__ Sb,
                                                        int M) {
    const int wave = threadIdx.x >> 6;
    const int lane = threadIdx.x & 63;
    const int r    = lane & 15;
    const int kg   = lane >> 4;
    const int m0   = blockIdx.x * 64;
    const int wc   = wave * 64;

    f32x4 acc[4][4];
    #pragma unroll
    for (int i = 0; i < 4; ++i)
        #pragma unroll
        for (int j = 0; j < 4; ++j)
            acc[i][j] = (f32x4)0.f;

    #pragma unroll
    for (int k0 = 0; k0 < K_DIM; k0 += 32) {
        bf16x8 a[4], b[4];
        #pragma unroll
        for (int mi = 0; mi < 4; ++mi) {
            int row = m0 + mi * 16 + r;
            row = row < M ? row : (M - 1);
            const float* p = X + (size_t)row * K_DIM + k0 + kg * 8;
            f32x4 lo = *reinterpret_cast<const f32x4*>(p);
            f32x4 hi = *reinterpret_cast<const f32x4*>(p + 4);
            bf16x8 v;
            v[0] = f32_to_bf16s(lo[0]); v[1] = f32_to_bf16s(lo[1]);
            v[2] = f32_to_bf16s(lo[2]); v[3] = f32_to_bf16s(lo[3]);
            v[4] = f32_to_bf16s(hi[0]); v[5] = f32_to_bf16s(hi[1]);
            v[6] = f32_to_bf16s(hi[2]); v[7] = f32_to_bf16s(hi[3]);
            a[mi] = v;
        }
        #pragma unroll
        for (int ni = 0; ni < 4; ++ni) {
            const short* q = g_Wt + (size_t)(wc + ni * 16 + r) * K_DIM + k0 + kg * 8;
            b[ni] = *reinterpret_cast<const bf16x8*>(q);
        }
        #pragma unroll
        for (int mi = 0; mi < 4; ++mi)
            #pragma unroll
            for (int ni = 0; ni < 4; ++ni)
                acc[mi][ni] = __builtin_amdgcn_mfma_f32_16x16x32_bf16(a[mi], b[ni], acc[mi][ni], 0, 0, 0);
    }

    #pragma unroll
    for (int mi = 0; mi < 4; ++mi) {
        #pragma unroll
        for (int reg = 0; reg < 4; ++reg) {
            const int row = m0 + mi * 16 + kg * 4 + reg;
            if (row < M) {
                #pragma unroll
                for (int ni = 0; ni < 4; ++ni)
                    Sb[(size_t)row * N_DIM + wc + ni * 16 + r] = f32_to_bf16s(acc[mi][ni][reg]);
            }
        }
    }
}

// ---------------------------------------------------------------------------
// CSR build (by dst): count -> 3-stage scan -> fill
// ---------------------------------------------------------------------------
__global__ __launch_bounds__(256) void count_kernel(const int* __restrict__ edst,
                                                    int* __restrict__ counts, int E) {
    int e = blockIdx.x * 256 + threadIdx.x;
    if (e < E) atomicAdd(&counts[edst[e]], 1);
}

#define SCAN_NB ((N_NODES + 255) / 256)   // 391

__global__ __launch_bounds__(256) void scan1_kernel(const int* __restrict__ counts) {
    __shared__ int wsum[4];
    const int i = blockIdx.x * 256 + threadIdx.x;
    int v = (i < N_NODES) ? counts[i] : 0;
    #pragma unroll
    for (int st = 32; st > 0; st >>= 1) v += __shfl_down(v, st, 64);
    if ((threadIdx.x & 63) == 0) wsum[threadIdx.x >> 6] = v;
    __syncthreads();
    if (threadIdx.x == 0) g_bsums[blockIdx.x] = wsum[0] + wsum[1] + wsum[2] + wsum[3];
}

__global__ __launch_bounds__(512) void scan2_kernel() {
    __shared__ int s[512];
    const int t = threadIdx.x;
    int v = (t < SCAN_NB) ? g_bsums[t] : 0;
    s[t] = v;
    __syncthreads();
    for (int st = 1; st < 512; st <<= 1) {
        int u = (t >= st) ? s[t - st] : 0;
        __syncthreads();
        s[t] += u;
        __syncthreads();
    }
    g_boff[t] = s[t] - v;   // exclusive prefix
}

// offsets[i+1] = inclusive prefix; cursor[i] = exclusive prefix (fill cursor seed)
__global__ __launch_bounds__(256) void scan3_kernel(const int* __restrict__ counts,
                                                    int* __restrict__ offsets,
                                                    int* __restrict__ cursor) {
    __shared__ int s[256];
    const int t = threadIdx.x;
    const int i = blockIdx.x * 256 + t;
    int v = (i < N_NODES) ? counts[i] : 0;
    s[t] = v;
    __syncthreads();
    for (int st = 1; st < 256; st <<= 1) {
        int u = (t >= st) ? s[t - st] : 0;
        __syncthreads();
        s[t] += u;
        __syncthreads();
    }
    if (i < N_NODES) {
        int inc = g_boff[blockIdx.x] + s[t];
        offsets[i + 1] = inc;
        cursor[i]      = inc - v;
    }
    if (i == 0) offsets[0] = 0;
}

__global__ __launch_bounds__(256) void fill_kernel(const int* __restrict__ esrc,
                                                   const int* __restrict__ edst,
                                                   const float* __restrict__ ew,
                                                   int* __restrict__ cursor,
                                                   int2* __restrict__ csr, int E) {
    int e = blockIdx.x * 256 + threadIdx.x;
    if (e >= E) return;
    int pos = atomicAdd(&cursor[edst[e]], 1);
    csr[pos] = make_int2(esrc[e], __float_as_int(ew[e]));
}

// ---------------------------------------------------------------------------
// Gather: one wave per dst node. supp is bf16 (512 B/row, 8 B/lane).
// 2 edges per iteration for memory-level parallelism. Single fp32 out write.
// ---------------------------------------------------------------------------
__global__ __launch_bounds__(256) void gather_kernel(const short* __restrict__ Sb,
                                                     const float* __restrict__ bias,
                                                     const int* __restrict__ offsets,
                                                     const int2* __restrict__ csr,
                                                     float* __restrict__ out) {
    const int tid  = threadIdx.x;
    const int node = blockIdx.x * 4 + (tid >> 6);
    if (node >= N_NODES) return;
    const int lane = tid & 63;

    const int row = offsets[node];
    const int end = offsets[node + 1];

    f32x4 acc = *reinterpret_cast<const f32x4*>(bias + lane * 4);

    int j = row;
    for (; j + 2 <= end; j += 2) {
        const int2 p0 = csr[j];
        const int2 p1 = csr[j + 1];
        const bf16x4 v0 = *reinterpret_cast<const bf16x4*>(Sb + (size_t)p0.x * N_DIM + lane * 4);
        const bf16x4 v1 = *reinterpret_cast<const bf16x4*>(Sb + (size_t)p1.x * N_DIM + lane * 4);
        const float w0 = __int_as_float(p0.y);
        const float w1 = __int_as_float(p1.y);
        #pragma unroll
        for (int c = 0; c < 4; ++c)
            acc[c] += bf16s_to_f32(v0[c]) * w0 + bf16s_to_f32(v1[c]) * w1;
    }
    if (j < end) {
        const int2 p = csr[j];
        const bf16x4 v = *reinterpret_cast<const bf16x4*>(Sb + (size_t)p.x * N_DIM + lane * 4);
        const float w = __int_as_float(p.y);
        #pragma unroll
        for (int c = 0; c < 4; ++c)
            acc[c] += bf16s_to_f32(v[c]) * w;
    }

    *reinterpret_cast<f32x4*>(out + (size_t)node * N_DIM + lane * 4) = acc;
}

// ---------------------------------------------------------------------------
// Fallback (ws too small): atomic scatter path on bf16 supp
// ---------------------------------------------------------------------------
__global__ __launch_bounds__(256) void init_out_kernel(float* __restrict__ out,
                                                       const float* __restrict__ bias,
                                                       int total) {
    int i = blockIdx.x * 256 + threadIdx.x;
    if (i < total) out[i] = bias[i & (N_DIM - 1)];
}

__global__ __launch_bounds__(256) void scatter_kernel(const short* __restrict__ Sb,
                                                      const float* __restrict__ ew,
                                                      const int* __restrict__ esrc,
                                                      const int* __restrict__ edst,
                                                      float* __restrict__ out, int E) {
    const int tid  = threadIdx.x;
    const int e    = blockIdx.x * 4 + (tid >> 6);
    if (e >= E) return;
    const int lane = tid & 63;
    const int   s = esrc[e];
    const int   d = edst[e];
    const float w = ew[e];
    const bf16x4 v = *reinterpret_cast<const bf16x4*>(Sb + (size_t)s * N_DIM + lane * 4);
    float* o = out + (size_t)d * N_DIM + lane * 4;
    unsafeAtomicAdd(o + 0, bf16s_to_f32(v[0]) * w);
    unsafeAtomicAdd(o + 1, bf16s_to_f32(v[1]) * w);
    unsafeAtomicAdd(o + 2, bf16s_to_f32(v[2]) * w);
    unsafeAtomicAdd(o + 3, bf16s_to_f32(v[3]) * w);
}

// ---------------------------------------------------------------------------
extern "C" void kernel_launch(void* const* d_in, const int* in_sizes, int n_in,
                              void* d_out, int out_size, void* d_ws, size_t ws_size,
                              hipStream_t stream) {
    const float* x      = (const float*)d_in[0];
    const float* weight = (const float*)d_in[1];
    const float* bias   = (const float*)d_in[2];
    const float* ew     = (const float*)d_in[3];
    const int*   esrc   = (const int*)d_in[4];
    const int*   edst   = (const int*)d_in[5];
    float*       out    = (float*)d_out;

    // Workspace layout
    char*  ws     = (char*)d_ws;
    const size_t SUPP_B = ((size_t)N_NODES * N_DIM * 2 + 255) & ~(size_t)255;  // bf16 supp
    const size_t CNT_B  = (size_t)N_NODES * 4;
    const size_t OFF_B  = ((size_t)(N_NODES + 1) * 4 + 15) & ~(size_t)15;
    const size_t CSR_B  = (size_t)N_EDGES * 8;

    short* supp    = (short*)(ws);
    int*   counts  = (int*)  (ws + SUPP_B);
    int*   cursor  = (int*)  (ws + SUPP_B + CNT_B);
    int*   offsets = (int*)  (ws + SUPP_B + 2 * CNT_B);
    int2*  csr     = (int2*) (ws + SUPP_B + 2 * CNT_B + OFF_B);
    const size_t NEEDED = SUPP_B + 2 * CNT_B + OFF_B + CSR_B;

    // 1) Wt = bf16(W^T); supp(bf16) = x @ W via MFMA
    convert_w_kernel<<<N_DIM, 256, 0, stream>>>(weight);
    mfma_gemm_kernel<<<(N_NODES + 63) / 64, 256, 0, stream>>>(x, supp, N_NODES);

    if (ws_size >= NEEDED) {
        (void)hipMemsetAsync(counts, 0, CNT_B, stream);
        count_kernel<<<(N_EDGES + 255) / 256, 256, 0, stream>>>(edst, counts, N_EDGES);
        scan1_kernel<<<SCAN_NB, 256, 0, stream>>>(counts);
        scan2_kernel<<<1, 512, 0, stream>>>();
        scan3_kernel<<<SCAN_NB, 256, 0, stream>>>(counts, offsets, cursor);
        fill_kernel<<<(N_EDGES + 255) / 256, 256, 0, stream>>>(esrc, edst, ew,
                                                               cursor, csr, N_EDGES);
        gather_kernel<<<(N_NODES + 3) / 4, 256, 0, stream>>>(supp, bias, offsets, csr, out);
    } else {
        int total = N_NODES * N_DIM;
        init_out_kernel<<<(total + 255) / 256, 256, 0, stream>>>(out, bias, total);
        scatter_kernel<<<(N_EDGES + 3) / 4, 256, 0, stream>>>(supp, ew, esrc, edst, out, N_EDGES);
    }
}

// Round 10
// 377.523 us; speedup vs baseline: 7.9295x; 1.0969x over previous
//
#include <hip/hip_runtime.h>
#include <hip/hip_bf16.h>

#define N_NODES 100000
#define N_EDGES 800000
#define K_DIM 256
#define N_DIM 256

typedef __attribute__((ext_vector_type(8)))  short  bf16x8;   // 8 bf16 (4 VGPR)
typedef __attribute__((ext_vector_type(4)))  short  bf16x4;   // 4 bf16 (2 VGPR)
typedef __attribute__((ext_vector_type(4)))  float  f32x4;

__device__ short g_Wt[K_DIM * N_DIM];   // Wt[n][k] = bf16(W[k][n]), 128 KiB
__device__ int   g_bsums[512];
__device__ int   g_boff[512];

static __device__ inline short f32_to_bf16s(float f) {
    __bf16 h = (__bf16)f;                       // RNE convert
    return __builtin_bit_cast(short, h);
}
static __device__ inline float bf16s_to_f32(short s) {
    unsigned int u = ((unsigned int)(unsigned short)s) << 16;
    return __uint_as_float(u);
}

// ---------------------------------------------------------------------------
// W transpose+convert: Wt[n][k] = bf16(W[k][n]).
// ---------------------------------------------------------------------------
__global__ __launch_bounds__(256) void convert_w_kernel(const float* __restrict__ W) {
    const int n = blockIdx.x;
    const int k = threadIdx.x;
    g_Wt[n * K_DIM + k] = f32_to_bf16s(W[(size_t)k * N_DIM + n]);
}

// ---------------------------------------------------------------------------
// MFMA GEMM with LDS-staged A: S(bf16) = X @ W, bf16 16x16x32, fp32 accum.
// Block: 256 thr / 4 waves. BM=64 rows, full N=256 (wave w -> cols w*64..+63).
// A tile (64 rows x 32 k, fp32, 8 KB) staged via global_load_lds (16B/lane,
// coalesced), double-buffered. Swizzle: 16B-chunk index c (0..7 within a
// 128B row) stored at c ^ (row&7); global source pre-swizzled, ds_read
// applies the same XOR (both-sides rule, m104/m173/m201).
// B frags read direct from g_Wt (L2-resident, one 64B line per col).
// C/D: col = lane&15, row = (lane>>4)*4 + reg   [m89-verified]
// ---------------------------------------------------------------------------
#define GBM 64
#define GBK 32

__global__ __launch_bounds__(256) void mfma_gemm_kernel(const float* __restrict__ X,
                                                        short* __restrict__ Sb,
                                                        int M) {
    __shared__ float A_lds[2][GBM * GBK];   // 2 x 8 KB

    const int tid  = threadIdx.x;
    const int wave = tid >> 6;
    const int lane = tid & 63;
    const int r    = lane & 15;
    const int kg   = lane >> 4;
    const int m0   = blockIdx.x * GBM;
    const int wc   = wave * 64;

    f32x4 acc[4][4];
    #pragma unroll
    for (int i = 0; i < 4; ++i)
        #pragma unroll
        for (int j = 0; j < 4; ++j)
            acc[i][j] = (f32x4)0.f;

    // Stage one 64x32 fp32 tile into A_lds[buf]. 512 16B-chunks, 2/thread.
    // chunk d: row = d>>3, c = d&7 (phys chunk), logical chunk c' = c^(row&7).
    auto stage = [&](int buf, int k0) {
        #pragma unroll
        for (int p = 0; p < 2; ++p) {
            const int d   = p * 256 + tid;
            const int row = d >> 3;
            const int cc  = (d & 7) ^ (row & 7);
            int gr = m0 + row;
            gr = gr < M ? gr : (M - 1);
            const float* gp = X + (size_t)gr * K_DIM + k0 + cc * 4;
            float* lp = &A_lds[buf][d * 4];
            __builtin_amdgcn_global_load_lds(
                (const __attribute__((address_space(1))) void*)gp,
                (__attribute__((address_space(3))) void*)lp, 16, 0, 0);
        }
    };

    stage(0, 0);
    __syncthreads();

    for (int t = 0; t < K_DIM / GBK; ++t) {
        const int cur = t & 1;
        if (t + 1 < K_DIM / GBK) stage(cur ^ 1, (t + 1) * GBK);

        const int k0 = t * GBK;

        // A frags from LDS (swizzled ds_read_b128 x2 per mi) + cvt to bf16
        bf16x8 a[4];
        #pragma unroll
        for (int mi = 0; mi < 4; ++mi) {
            const int rl = mi * 16 + r;                 // 0..63
            const int c0 = (kg * 2 + 0) ^ (rl & 7);
            const int c1 = (kg * 2 + 1) ^ (rl & 7);
            f32x4 lo = *reinterpret_cast<const f32x4*>(&A_lds[cur][rl * GBK + c0 * 4]);
            f32x4 hi = *reinterpret_cast<const f32x4*>(&A_lds[cur][rl * GBK + c1 * 4]);
            bf16x8 v;
            v[0] = f32_to_bf16s(lo[0]); v[1] = f32_to_bf16s(lo[1]);
            v[2] = f32_to_bf16s(lo[2]); v[3] = f32_to_bf16s(lo[3]);
            v[4] = f32_to_bf16s(hi[0]); v[5] = f32_to_bf16s(hi[1]);
            v[6] = f32_to_bf16s(hi[2]); v[7] = f32_to_bf16s(hi[3]);
            a[mi] = v;
        }

        // B frags direct from L2-resident g_Wt
        bf16x8 b[4];
        #pragma unroll
        for (int ni = 0; ni < 4; ++ni) {
            const short* q = g_Wt + (size_t)(wc + ni * 16 + r) * K_DIM + k0 + kg * 8;
            b[ni] = *reinterpret_cast<const bf16x8*>(q);
        }

        #pragma unroll
        for (int mi = 0; mi < 4; ++mi)
            #pragma unroll
            for (int ni = 0; ni < 4; ++ni)
                acc[mi][ni] = __builtin_amdgcn_mfma_f32_16x16x32_bf16(a[mi], b[ni], acc[mi][ni], 0, 0, 0);

        __syncthreads();   // drains this iter's stage (vmcnt) + ds_reads (lgkmcnt)
    }

    #pragma unroll
    for (int mi = 0; mi < 4; ++mi) {
        #pragma unroll
        for (int reg = 0; reg < 4; ++reg) {
            const int row = m0 + mi * 16 + kg * 4 + reg;
            if (row < M) {
                #pragma unroll
                for (int ni = 0; ni < 4; ++ni)
                    Sb[(size_t)row * N_DIM + wc + ni * 16 + r] = f32_to_bf16s(acc[mi][ni][reg]);
            }
        }
    }
}

// ---------------------------------------------------------------------------
// CSR build (by dst): count -> 3-stage scan -> fill
// ---------------------------------------------------------------------------
__global__ __launch_bounds__(256) void count_kernel(const int* __restrict__ edst,
                                                    int* __restrict__ counts, int E) {
    int e = blockIdx.x * 256 + threadIdx.x;
    if (e < E) atomicAdd(&counts[edst[e]], 1);
}

#define SCAN_NB ((N_NODES + 255) / 256)   // 391

__global__ __launch_bounds__(256) void scan1_kernel(const int* __restrict__ counts) {
    __shared__ int wsum[4];
    const int i = blockIdx.x * 256 + threadIdx.x;
    int v = (i < N_NODES) ? counts[i] : 0;
    #pragma unroll
    for (int st = 32; st > 0; st >>= 1) v += __shfl_down(v, st, 64);
    if ((threadIdx.x & 63) == 0) wsum[threadIdx.x >> 6] = v;
    __syncthreads();
    if (threadIdx.x == 0) g_bsums[blockIdx.x] = wsum[0] + wsum[1] + wsum[2] + wsum[3];
}

__global__ __launch_bounds__(512) void scan2_kernel() {
    __shared__ int s[512];
    const int t = threadIdx.x;
    int v = (t < SCAN_NB) ? g_bsums[t] : 0;
    s[t] = v;
    __syncthreads();
    for (int st = 1; st < 512; st <<= 1) {
        int u = (t >= st) ? s[t - st] : 0;
        __syncthreads();
        s[t] += u;
        __syncthreads();
    }
    g_boff[t] = s[t] - v;   // exclusive prefix
}

// offsets[i+1] = inclusive prefix; cursor[i] = exclusive prefix (fill cursor seed)
__global__ __launch_bounds__(256) void scan3_kernel(const int* __restrict__ counts,
                                                    int* __restrict__ offsets,
                                                    int* __restrict__ cursor) {
    __shared__ int s[256];
    const int t = threadIdx.x;
    const int i = blockIdx.x * 256 + t;
    int v = (i < N_NODES) ? counts[i] : 0;
    s[t] = v;
    __syncthreads();
    for (int st = 1; st < 256; st <<= 1) {
        int u = (t >= st) ? s[t - st] : 0;
        __syncthreads();
        s[t] += u;
        __syncthreads();
    }
    if (i < N_NODES) {
        int inc = g_boff[blockIdx.x] + s[t];
        offsets[i + 1] = inc;
        cursor[i]      = inc - v;
    }
    if (i == 0) offsets[0] = 0;
}

__global__ __launch_bounds__(256) void fill_kernel(const int* __restrict__ esrc,
                                                   const int* __restrict__ edst,
                                                   const float* __restrict__ ew,
                                                   int* __restrict__ cursor,
                                                   int2* __restrict__ csr, int E) {
    int e = blockIdx.x * 256 + threadIdx.x;
    if (e >= E) return;
    int pos = atomicAdd(&cursor[edst[e]], 1);
    csr[pos] = make_int2(esrc[e], __float_as_int(ew[e]));
}

// ---------------------------------------------------------------------------
// Gather: one wave per dst node. supp is bf16 (512 B/row, 8 B/lane).
// 2 edges per iteration for memory-level parallelism. Single fp32 out write.
// ---------------------------------------------------------------------------
__global__ __launch_bounds__(256) void gather_kernel(const short* __restrict__ Sb,
                                                     const float* __restrict__ bias,
                                                     const int* __restrict__ offsets,
                                                     const int2* __restrict__ csr,
                                                     float* __restrict__ out) {
    const int tid  = threadIdx.x;
    const int node = blockIdx.x * 4 + (tid >> 6);
    if (node >= N_NODES) return;
    const int lane = tid & 63;

    const int row = offsets[node];
    const int end = offsets[node + 1];

    f32x4 acc = *reinterpret_cast<const f32x4*>(bias + lane * 4);

    int j = row;
    for (; j + 2 <= end; j += 2) {
        const int2 p0 = csr[j];
        const int2 p1 = csr[j + 1];
        const bf16x4 v0 = *reinterpret_cast<const bf16x4*>(Sb + (size_t)p0.x * N_DIM + lane * 4);
        const bf16x4 v1 = *reinterpret_cast<const bf16x4*>(Sb + (size_t)p1.x * N_DIM + lane * 4);
        const float w0 = __int_as_float(p0.y);
        const float w1 = __int_as_float(p1.y);
        #pragma unroll
        for (int c = 0; c < 4; ++c)
            acc[c] += bf16s_to_f32(v0[c]) * w0 + bf16s_to_f32(v1[c]) * w1;
    }
    if (j < end) {
        const int2 p = csr[j];
        const bf16x4 v = *reinterpret_cast<const bf16x4*>(Sb + (size_t)p.x * N_DIM + lane * 4);
        const float w = __int_as_float(p.y);
        #pragma unroll
        for (int c = 0; c < 4; ++c)
            acc[c] += bf16s_to_f32(v[c]) * w;
    }

    *reinterpret_cast<f32x4*>(out + (size_t)node * N_DIM + lane * 4) = acc;
}

// ---------------------------------------------------------------------------
// Fallback (ws too small): atomic scatter path on bf16 supp
// ---------------------------------------------------------------------------
__global__ __launch_bounds__(256) void init_out_kernel(float* __restrict__ out,
                                                       const float* __restrict__ bias,
                                                       int total) {
    int i = blockIdx.x * 256 + threadIdx.x;
    if (i < total) out[i] = bias[i & (N_DIM - 1)];
}

__global__ __launch_bounds__(256) void scatter_kernel(const short* __restrict__ Sb,
                                                      const float* __restrict__ ew,
                                                      const int* __restrict__ esrc,
                                                      const int* __restrict__ edst,
                                                      float* __restrict__ out, int E) {
    const int tid  = threadIdx.x;
    const int e    = blockIdx.x * 4 + (tid >> 6);
    if (e >= E) return;
    const int lane = tid & 63;
    const int   s = esrc[e];
    const int   d = edst[e];
    const float w = ew[e];
    const bf16x4 v = *reinterpret_cast<const bf16x4*>(Sb + (size_t)s * N_DIM + lane * 4);
    float* o = out + (size_t)d * N_DIM + lane * 4;
    unsafeAtomicAdd(o + 0, bf16s_to_f32(v[0]) * w);
    unsafeAtomicAdd(o + 1, bf16s_to_f32(v[1]) * w);
    unsafeAtomicAdd(o + 2, bf16s_to_f32(v[2]) * w);
    unsafeAtomicAdd(o + 3, bf16s_to_f32(v[3]) * w);
}

// ---------------------------------------------------------------------------
extern "C" void kernel_launch(void* const* d_in, const int* in_sizes, int n_in,
                              void* d_out, int out_size, void* d_ws, size_t ws_size,
                              hipStream_t stream) {
    const float* x      = (const float*)d_in[0];
    const float* weight = (const float*)d_in[1];
    const float* bias   = (const float*)d_in[2];
    const float* ew     = (const float*)d_in[3];
    const int*   esrc   = (const int*)d_in[4];
    const int*   edst   = (const int*)d_in[5];
    float*       out    = (float*)d_out;

    // Workspace layout
    char*  ws     = (char*)d_ws;
    const size_t SUPP_B = ((size_t)N_NODES * N_DIM * 2 + 255) & ~(size_t)255;  // bf16 supp
    const size_t CNT_B  = (size_t)N_NODES * 4;
    const size_t OFF_B  = ((size_t)(N_NODES + 1) * 4 + 15) & ~(size_t)15;
    const size_t CSR_B  = (size_t)N_EDGES * 8;

    short* supp    = (short*)(ws);
    int*   counts  = (int*)  (ws + SUPP_B);
    int*   cursor  = (int*)  (ws + SUPP_B + CNT_B);
    int*   offsets = (int*)  (ws + SUPP_B + 2 * CNT_B);
    int2*  csr     = (int2*) (ws + SUPP_B + 2 * CNT_B + OFF_B);
    const size_t NEEDED = SUPP_B + 2 * CNT_B + OFF_B + CSR_B;

    // 1) Wt = bf16(W^T); supp(bf16) = x @ W via MFMA (LDS-staged A)
    convert_w_kernel<<<N_DIM, 256, 0, stream>>>(weight);
    mfma_gemm_kernel<<<(N_NODES + GBM - 1) / GBM, 256, 0, stream>>>(x, supp, N_NODES);

    if (ws_size >= NEEDED) {
        (void)hipMemsetAsync(counts, 0, CNT_B, stream);
        count_kernel<<<(N_EDGES + 255) / 256, 256, 0, stream>>>(edst, counts, N_EDGES);
        scan1_kernel<<<SCAN_NB, 256, 0, stream>>>(counts);
        scan2_kernel<<<1, 512, 0, stream>>>();
        scan3_kernel<<<SCAN_NB, 256, 0, stream>>>(counts, offsets, cursor);
        fill_kernel<<<(N_EDGES + 255) / 256, 256, 0, stream>>>(esrc, edst, ew,
                                                               cursor, csr, N_EDGES);
        gather_kernel<<<(N_NODES + 3) / 4, 256, 0, stream>>>(supp, bias, offsets, csr, out);
    } else {
        int total = N_NODES * N_DIM;
        init_out_kernel<<<(total + 255) / 256, 256, 0, stream>>>(out, bias, total);
        scatter_kernel<<<(N_EDGES + 3) / 4, 256, 0, stream>>>(supp, ew, esrc, edst, out, N_EDGES);
    }
}